// Round 4
// baseline (608.078 us; speedup 1.0000x reference)
//
#include <hip/hip_runtime.h>
#include <hip/hip_bf16.h>

// ---------- types ----------
typedef __attribute__((ext_vector_type(8))) short bf8_t;   // 8 bf16 in 4 VGPRs
typedef __attribute__((ext_vector_type(4))) float f4_t;    // MFMA accumulator

#define MFMA16(a, b, c) __builtin_amdgcn_mfma_f32_16x16x32_bf16((a), (b), (c), 0, 0, 0)

static __device__ inline unsigned short f2bf(float f) {
    unsigned int u = __float_as_uint(f);
    unsigned int r = 0x7fffu + ((u >> 16) & 1u);
    return (unsigned short)((u + r) >> 16);
}

// ---------- mask probe + additive-bias build (single block) ----------
__global__ void k_bias(const void* __restrict__ maskp, float* __restrict__ fbias) {
    __shared__ int s_int, s_flt;
    const unsigned int* mw = (const unsigned int*)maskp;
    if (threadIdx.x == 0) { s_int = 1; s_flt = 1; }
    __syncthreads();
    int li = 1, lf = 1;
    for (int i = threadIdx.x; i < 2048; i += 1024) {
        unsigned int v = mw[i];
        if (v != 0u && v != 1u) li = 0;
        if (v != 0u && v != 0x3F800000u) lf = 0;
    }
    if (!li) atomicAnd(&s_int, 0);
    if (!lf) atomicAnd(&s_flt, 0);
    __syncthreads();
    const int flag = s_int ? 0 : (s_flt ? 1 : 2);
    const int*           mi = (const int*)maskp;
    const float*         mf = (const float*)maskp;
    const unsigned char* mb = (const unsigned char*)maskp;
    for (int i = threadIdx.x; i < 8192; i += 1024) {
        bool m = (flag == 0) ? (mi[i] != 0) : (flag == 1) ? (mf[i] != 0.0f) : (mb[i] != 0);
        fbias[i] = m ? -1e30f : 0.0f;
    }
}

// ---------- fp32 -> bf16 convert (x) ----------
__global__ void k_cvt(const float* __restrict__ x, unsigned short* __restrict__ xb, int n4) {
    int i = blockIdx.x * blockDim.x + threadIdx.x;
    if (i < n4) {
        float4 v = ((const float4*)x)[i];
        ushort4 o;
        o.x = f2bf(v.x); o.y = f2bf(v.y); o.z = f2bf(v.z); o.w = f2bf(v.w);
        ((ushort4*)xb)[i] = o;
    }
}

// ---------- W [K][N] fp32 -> WT [N][K] bf16 (4 matrices) ----------
__global__ void k_transw(const float* __restrict__ Wq, const float* __restrict__ Wk,
                         const float* __restrict__ Wv, const float* __restrict__ Wo,
                         unsigned short* __restrict__ WT) {
    __shared__ float tile[32][33];
    const float* W = (blockIdx.z == 0) ? Wq : (blockIdx.z == 1) ? Wk : (blockIdx.z == 2) ? Wv : Wo;
    unsigned short* out = WT + (size_t)blockIdx.z * 1024 * 1024;
    int n_r = blockIdx.x * 32 + threadIdx.x;
    int k_r = blockIdx.y * 32 + threadIdx.y;
    #pragma unroll
    for (int j = 0; j < 32; j += 8)
        tile[threadIdx.y + j][threadIdx.x] = W[(size_t)(k_r + j) * 1024 + n_r];
    __syncthreads();
    int k_w = blockIdx.y * 32 + threadIdx.x;
    int n_w = blockIdx.x * 32 + threadIdx.y;
    #pragma unroll
    for (int j = 0; j < 32; j += 8)
        out[(size_t)(n_w + j) * 1024 + k_w] = f2bf(tile[threadIdx.x][threadIdx.y + j]);
}

// ---------- GEMM: C[8192][1024] = A_bf16 @ WT^T (+bias) ----------
template <int MODE>
__global__ __launch_bounds__(256) void k_gemm(
    const unsigned short* __restrict__ A,
    const unsigned short* __restrict__ WTb,
    const float* __restrict__ b0, const float* __restrict__ b1, const float* __restrict__ b2,
    void* __restrict__ outp)
{
    __shared__ unsigned short Als[128][40];
    __shared__ unsigned short Bls[128][40];
    const int tid  = threadIdx.x;
    const int lane = tid & 63;
    const int w    = tid >> 6;
    const int wr   = w >> 1, wc = w & 1;
    const int lg   = lane >> 4, lr = lane & 15;
    const int bm   = blockIdx.y * 128;
    const int bn   = blockIdx.x * 128;
    const unsigned short* WT = WTb + (MODE == 0 ? (size_t)blockIdx.z * (1024 * 1024) : 0);

    f4_t acc[4][4];
    const f4_t z4 = {0.f, 0.f, 0.f, 0.f};
    #pragma unroll
    for (int i = 0; i < 4; ++i)
        #pragma unroll
        for (int j = 0; j < 4; ++j) acc[i][j] = z4;

    const int srow = tid >> 2;
    const int scol = (tid & 3) * 8;

    for (int k0 = 0; k0 < 1024; k0 += 32) {
        __syncthreads();
        #pragma unroll
        for (int p = 0; p < 2; ++p) {
            int r = srow + p * 64;
            *(bf8_t*)(&Als[r][scol]) = *(const bf8_t*)(A  + (size_t)(bm + r) * 1024 + k0 + scol);
            *(bf8_t*)(&Bls[r][scol]) = *(const bf8_t*)(WT + (size_t)(bn + r) * 1024 + k0 + scol);
        }
        __syncthreads();

        bf8_t af[4], bfv[4];
        #pragma unroll
        for (int i = 0; i < 4; ++i) af[i]  = *(const bf8_t*)(&Als[wr * 64 + i * 16 + lr][lg * 8]);
        #pragma unroll
        for (int j = 0; j < 4; ++j) bfv[j] = *(const bf8_t*)(&Bls[wc * 64 + j * 16 + lr][lg * 8]);
        #pragma unroll
        for (int i = 0; i < 4; ++i)
            #pragma unroll
            for (int j = 0; j < 4; ++j)
                acc[i][j] = MFMA16(af[i], bfv[j], acc[i][j]);
    }

    if (MODE == 0) {
        unsigned short* O = (unsigned short*)outp + (size_t)blockIdx.z * (8192 * 1024);
        const float* bias = (blockIdx.z == 0) ? b0 : (blockIdx.z == 1) ? b1 : b2;
        const float sc = (blockIdx.z == 0) ? 0.18033688011112042f : 1.0f; // 0.125*log2(e)
        #pragma unroll
        for (int i = 0; i < 4; ++i)
            #pragma unroll
            for (int j = 0; j < 4; ++j)
                #pragma unroll
                for (int r = 0; r < 4; ++r) {
                    int row = bm + wr * 64 + i * 16 + lg * 4 + r;
                    int col = bn + wc * 64 + j * 16 + lr;
                    float v = (acc[i][j][r] + bias[col]) * sc;
                    int b = row >> 11, s = row & 2047, h = col >> 6, d = col & 63;
                    O[(((size_t)(b * 16 + h)) * 2048 + s) * 64 + d] = f2bf(v);
                }
    } else {
        float* O = (float*)outp;
        #pragma unroll
        for (int i = 0; i < 4; ++i)
            #pragma unroll
            for (int j = 0; j < 4; ++j)
                #pragma unroll
                for (int r = 0; r < 4; ++r) {
                    int row = bm + wr * 64 + i * 16 + lg * 4 + r;
                    int col = bn + wc * 64 + j * 16 + lr;
                    O[(size_t)row * 1024 + col] = acc[i][j][r] + b0[col];
                }
    }
}

// ---------- V [bh][s][d] -> VT [bh][d][s] ----------
__global__ __launch_bounds__(256) void k_vtrans(const unsigned short* __restrict__ V,
                                                unsigned short* __restrict__ VT) {
    __shared__ unsigned short t[64][72];
    const int bh = blockIdx.y;
    const int s0 = blockIdx.x * 64;
    const int tid = threadIdx.x;
    const int sr = tid >> 2;
    const int c0 = (tid & 3) * 16;
    const unsigned short* src = V + ((size_t)bh * 2048 + s0 + sr) * 64 + c0;
    bf8_t a = *(const bf8_t*)src;
    bf8_t bq = *(const bf8_t*)(src + 8);
    #pragma unroll
    for (int e = 0; e < 8; ++e) {
        t[c0 + e][sr]     = (unsigned short)a[e];
        t[c0 + 8 + e][sr] = (unsigned short)bq[e];
    }
    __syncthreads();
    unsigned short* dst = VT + ((size_t)bh * 64 + sr) * 2048 + s0 + c0;
    *(bf8_t*)dst       = *(const bf8_t*)&t[sr][c0];
    *(bf8_t*)(dst + 8) = *(const bf8_t*)&t[sr][c0 + 8];
}

// ---------- flash attention: reg-pipelined K, early V, XCD-grouped heads ----------
// grid 2048 x 256. 4 waves x 16 q-rows, KBLK=64. Q pre-scaled by 0.125*log2e.
__global__ __launch_bounds__(256, 1) void k_attn(
    const unsigned short* __restrict__ Q,    // [64][2048][64]
    const unsigned short* __restrict__ K,    // [64][2048][64]
    const unsigned short* __restrict__ VT,   // [64][64][2048]
    const float* __restrict__ fbias,         // [4][2048] 0/-1e30
    unsigned short* __restrict__ O)          // [8192][1024]
{
    __shared__ float sbias[2048];
    __shared__ unsigned short pls[4][16][72];
    const int tid  = threadIdx.x;
    const int lane = tid & 63;
    const int w    = tid >> 6;
    const int lg   = lane >> 4, lr = lane & 15;

    // XCD-bijective swizzle: XCD (id%8) owns heads [xcd*8, xcd*8+8) -> 4MB L2 set
    const int id  = blockIdx.x;
    const int bh  = (id & 7) * 8 + ((id >> 3) & 7);
    const int qt  = id >> 6;                  // 0..31
    const int b   = bh >> 4, h = bh & 15;
    const int q0  = qt * 64 + w * 16;
    const size_t base = (size_t)bh * (2048 * 64);

    // stage mask bias row for this batch into LDS (single barrier in kernel)
    {
        const float4* src = (const float4*)(fbias + b * 2048);
        float4* dst = (float4*)sbias;
        for (int i = tid; i < 512; i += 256) dst[i] = src[i];
    }
    __syncthreads();

    const bf8_t qf0 = *(const bf8_t*)(Q + base + (size_t)(q0 + lr) * 64 + lg * 8);
    const bf8_t qf1 = *(const bf8_t*)(Q + base + (size_t)(q0 + lr) * 64 + 32 + lg * 8);

    const f4_t z4 = {0.f, 0.f, 0.f, 0.f};
    f4_t oacc[4] = {z4, z4, z4, z4};
    float mrow = -1e30f;
    float lsum = 0.0f;

    const unsigned short* Krow = K + base + (size_t)lr * 64 + lg * 8;
    const unsigned short* Vrow = VT + (size_t)bh * (64 * 2048) + (size_t)lr * 2048 + lg * 8;
    unsigned short* pw = &pls[w][lr][0];
    const unsigned short* pr = &pls[w][lr][lg * 8];
    const int lg4 = lg * 4;

    bf8_t kA[4][2], kB[4][2];
    #pragma unroll
    for (int mf = 0; mf < 4; ++mf) {
        kA[mf][0] = *(const bf8_t*)(Krow + (size_t)(mf * 16) * 64);
        kA[mf][1] = *(const bf8_t*)(Krow + (size_t)(mf * 16) * 64 + 32);
    }

    auto step = [&](bf8_t (&kc)[4][2], bf8_t (&kn)[4][2], int k0) {
        // issue V(t) loads now; consumed after softmax (~600cy of cover)
        bf8_t vf[4][2];
        #pragma unroll
        for (int nf = 0; nf < 4; ++nf) {
            vf[nf][0] = *(const bf8_t*)(Vrow + (size_t)(nf * 16) * 2048 + k0);
            vf[nf][1] = *(const bf8_t*)(Vrow + (size_t)(nf * 16) * 2048 + k0 + 32);
        }
        // issue K(t+1) loads (register double-buffer; 8KB overread at end is benign)
        #pragma unroll
        for (int mf = 0; mf < 4; ++mf) {
            kn[mf][0] = *(const bf8_t*)(Krow + (size_t)(k0 + 64 + mf * 16) * 64);
            kn[mf][1] = *(const bf8_t*)(Krow + (size_t)(k0 + 64 + mf * 16) * 64 + 32);
        }
        // S^T = K·Q^T : lane holds S[key=lg*4+r][q=lr]
        f4_t s[4];
        #pragma unroll
        for (int mf = 0; mf < 4; ++mf) {
            f4_t zz = z4;
            zz = MFMA16(kc[mf][0], qf0, zz);
            zz = MFMA16(kc[mf][1], qf1, zz);
            s[mf] = zz;
        }
        // additive key mask from LDS
        #pragma unroll
        for (int mf = 0; mf < 4; ++mf) {
            float4 bv = *(const float4*)&sbias[k0 + mf * 16 + lg4];
            s[mf][0] += bv.x; s[mf][1] += bv.y; s[mf][2] += bv.z; s[mf][3] += bv.w;
        }
        // row max: 15 in-reg + 2 shuffles
        float m0 = fmaxf(fmaxf(s[0][0], s[0][1]), fmaxf(s[0][2], s[0][3]));
        float m1 = fmaxf(fmaxf(s[1][0], s[1][1]), fmaxf(s[1][2], s[1][3]));
        float m2 = fmaxf(fmaxf(s[2][0], s[2][1]), fmaxf(s[2][2], s[2][3]));
        float m3 = fmaxf(fmaxf(s[3][0], s[3][1]), fmaxf(s[3][2], s[3][3]));
        float smax = fmaxf(fmaxf(m0, m1), fmaxf(m2, m3));
        smax = fmaxf(smax, __shfl_xor(smax, 16));
        smax = fmaxf(smax, __shfl_xor(smax, 32));
        // defer-max rescale
        if (__any(smax > mrow)) {
            float mnew = fmaxf(mrow, smax);
            float c = exp2f(mrow - mnew);
            mrow = mnew;
            lsum *= c;
            #pragma unroll
            for (int r = 0; r < 4; ++r) {
                float cr = __shfl(c, lg4 + r);
                oacc[0][r] *= cr; oacc[1][r] *= cr; oacc[2][r] *= cr; oacc[3][r] *= cr;
            }
        }
        // P = exp2(S - m); denom; stash bf16 P (wave-local LDS)
        float bsum = 0.0f;
        #pragma unroll
        for (int mf = 0; mf < 4; ++mf) {
            ushort4 pk;
            float p0 = exp2f(s[mf][0] - mrow);
            float p1 = exp2f(s[mf][1] - mrow);
            float p2 = exp2f(s[mf][2] - mrow);
            float p3 = exp2f(s[mf][3] - mrow);
            bsum += (p0 + p1) + (p2 + p3);
            pk.x = f2bf(p0); pk.y = f2bf(p1); pk.z = f2bf(p2); pk.w = f2bf(p3);
            *(ushort4*)(pw + mf * 16 + lg4) = pk;
        }
        bsum += __shfl_xor(bsum, 16);
        bsum += __shfl_xor(bsum, 32);
        lsum += bsum;
        // PV: A = P[q][key] from LDS, B = V^T[d][key] from registers
        bf8_t pa0 = *(const bf8_t*)pr;
        bf8_t pa1 = *(const bf8_t*)(pr + 32);
        #pragma unroll
        for (int nf = 0; nf < 4; ++nf) {
            oacc[nf] = MFMA16(pa0, vf[nf][0], oacc[nf]);
            oacc[nf] = MFMA16(pa1, vf[nf][1], oacc[nf]);
        }
    };

    for (int t = 0; t < 2048; t += 128) {
        step(kA, kB, t);
        step(kB, kA, t + 64);
    }

    // normalize + write [B,S,D] bf16
    #pragma unroll
    for (int r = 0; r < 4; ++r) {
        float ls = __shfl(lsum, lg4 + r);
        float inv = 1.0f / ls;
        int srow = q0 + lg4 + r;
        size_t ob = ((size_t)(b * 2048 + srow)) * 1024 + h * 64;
        #pragma unroll
        for (int nf = 0; nf < 4; ++nf)
            O[ob + nf * 16 + lr] = f2bf(oacc[nf][r] * inv);
    }
}

// ---------- launch ----------
extern "C" void kernel_launch(void* const* d_in, const int* in_sizes, int n_in,
                              void* d_out, int out_size, void* d_ws, size_t ws_size,
                              hipStream_t stream) {
    const float* x  = (const float*)d_in[0];
    const void*  mask = d_in[1];
    const float* Wq = (const float*)d_in[2];
    const float* bq = (const float*)d_in[3];
    const float* Wk = (const float*)d_in[4];
    const float* bk = (const float*)d_in[5];
    const float* Wv = (const float*)d_in[6];
    const float* bv = (const float*)d_in[7];
    const float* Wo = (const float*)d_in[8];
    const float* bo = (const float*)d_in[9];

    char* ws = (char*)d_ws;
    float*          fbias = (float*)(ws + 1024);
    unsigned short* xb    = (unsigned short*)(ws + 65536);                // 16 MiB (reused as VT)
    unsigned short* wT    = (unsigned short*)(ws + 65536 + 16777216);     // 8 MiB
    unsigned short* qkv   = (unsigned short*)(ws + 65536 + 25165824);     // 48 MiB
    unsigned short* attnb = (unsigned short*)(ws + 65536 + 75497472);     // 16 MiB

    unsigned short* Qb = qkv;
    unsigned short* Kb = qkv + 8388608;
    unsigned short* Vb = qkv + 16777216;
    unsigned short* VT = xb;   // xb dead after QKV GEMM

    k_bias<<<1, 1024, 0, stream>>>(mask, fbias);
    k_cvt<<<8192, 256, 0, stream>>>(x, xb, 2097152);
    k_transw<<<dim3(32, 32, 4), dim3(32, 8), 0, stream>>>(Wq, Wk, Wv, Wo, wT);
    k_gemm<0><<<dim3(8, 64, 3), 256, 0, stream>>>(xb, wT, bq, bk, bv, (void*)qkv);
    k_vtrans<<<dim3(32, 64), 256, 0, stream>>>(Vb, VT);
    k_attn<<<2048, 256, 0, stream>>>(Qb, Kb, VT, fbias, attnb);
    k_gemm<1><<<dim3(8, 64, 1), 256, 0, stream>>>(attnb, wT + 3145728, bo, bo, bo, d_out);
}

// Round 5
// 282.658 us; speedup vs baseline: 2.1513x; 2.1513x over previous
//
#include <hip/hip_runtime.h>
#include <hip/hip_bf16.h>

// ---------- types ----------
typedef __attribute__((ext_vector_type(8))) short bf8_t;   // 8 bf16 in 4 VGPRs
typedef __attribute__((ext_vector_type(4))) float f4_t;    // MFMA accumulator

#define MFMA16(a, b, c) __builtin_amdgcn_mfma_f32_16x16x32_bf16((a), (b), (c), 0, 0, 0)

#if __has_builtin(__builtin_amdgcn_exp2f)
#define EXP2(x) __builtin_amdgcn_exp2f(x)
#else
#define EXP2(x) exp2f(x)
#endif

static __device__ inline unsigned short f2bf(float f) {
    unsigned int u = __float_as_uint(f);
    unsigned int r = 0x7fffu + ((u >> 16) & 1u);
    return (unsigned short)((u + r) >> 16);
}

// async global->LDS, 16B per lane; dest must be wave-uniform base + lane*16
static __device__ inline void gload16(const void* g, void* l) {
    __builtin_amdgcn_global_load_lds(
        (const __attribute__((address_space(1))) unsigned int*)g,
        (__attribute__((address_space(3))) unsigned int*)l, 16, 0, 0);
}

// ---------- mask probe + additive-bias build ----------
__global__ void k_bias(const void* __restrict__ maskp, float* __restrict__ fbias) {
    __shared__ int s_int, s_flt;
    const unsigned int* mw = (const unsigned int*)maskp;
    if (threadIdx.x == 0) { s_int = 1; s_flt = 1; }
    __syncthreads();
    int li = 1, lf = 1;
    for (int i = threadIdx.x; i < 2048; i += 1024) {
        unsigned int v = mw[i];
        if (v != 0u && v != 1u) li = 0;
        if (v != 0u && v != 0x3F800000u) lf = 0;
    }
    if (!li) atomicAnd(&s_int, 0);
    if (!lf) atomicAnd(&s_flt, 0);
    __syncthreads();
    const int flag = s_int ? 0 : (s_flt ? 1 : 2);
    const int*           mi = (const int*)maskp;
    const float*         mf = (const float*)maskp;
    const unsigned char* mb = (const unsigned char*)maskp;
    for (int i = threadIdx.x; i < 8192; i += 1024) {
        bool m = (flag == 0) ? (mi[i] != 0) : (flag == 1) ? (mf[i] != 0.0f) : (mb[i] != 0);
        fbias[i] = m ? -1e30f : 0.0f;
    }
}

// ---------- fp32 -> bf16 convert (x) ----------
__global__ void k_cvt(const float* __restrict__ x, unsigned short* __restrict__ xb, int n4) {
    int i = blockIdx.x * blockDim.x + threadIdx.x;
    if (i < n4) {
        float4 v = ((const float4*)x)[i];
        ushort4 o;
        o.x = f2bf(v.x); o.y = f2bf(v.y); o.z = f2bf(v.z); o.w = f2bf(v.w);
        ((ushort4*)xb)[i] = o;
    }
}

// ---------- W [K][N] fp32 -> WT [N][K] bf16 (4 matrices) ----------
__global__ void k_transw(const float* __restrict__ Wq, const float* __restrict__ Wk,
                         const float* __restrict__ Wv, const float* __restrict__ Wo,
                         unsigned short* __restrict__ WT) {
    __shared__ float tile[32][33];
    const float* W = (blockIdx.z == 0) ? Wq : (blockIdx.z == 1) ? Wk : (blockIdx.z == 2) ? Wv : Wo;
    unsigned short* out = WT + (size_t)blockIdx.z * 1024 * 1024;
    int n_r = blockIdx.x * 32 + threadIdx.x;
    int k_r = blockIdx.y * 32 + threadIdx.y;
    #pragma unroll
    for (int j = 0; j < 32; j += 8)
        tile[threadIdx.y + j][threadIdx.x] = W[(size_t)(k_r + j) * 1024 + n_r];
    __syncthreads();
    int k_w = blockIdx.y * 32 + threadIdx.x;
    int n_w = blockIdx.x * 32 + threadIdx.y;
    #pragma unroll
    for (int j = 0; j < 32; j += 8)
        out[(size_t)(n_w + j) * 1024 + k_w] = f2bf(tile[threadIdx.x][threadIdx.y + j]);
}

// ---------- GEMM: C[8192][1024] = A_bf16 @ WT^T (+bias), global_load_lds staging ----------
template <int MODE>
__global__ __launch_bounds__(256) void k_gemm(
    const unsigned short* __restrict__ A,
    const unsigned short* __restrict__ WTb,
    const float* __restrict__ b0, const float* __restrict__ b1, const float* __restrict__ b2,
    void* __restrict__ outp)
{
    __shared__ __align__(16) unsigned short Als[128][32];
    __shared__ __align__(16) unsigned short Bls[128][32];
    const int tid  = threadIdx.x;
    const int lane = tid & 63;
    const int w    = tid >> 6;
    const int wr   = w >> 1, wc = w & 1;
    const int lg   = lane >> 4, lr = lane & 15;
    const int bm   = blockIdx.y * 128;
    const int bn   = blockIdx.x * 128;
    const unsigned short* WT = WTb + (MODE == 0 ? (size_t)blockIdx.z * (1024 * 1024) : 0);

    f4_t acc[4][4];
    const f4_t z4 = {0.f, 0.f, 0.f, 0.f};
    #pragma unroll
    for (int i = 0; i < 4; ++i)
        #pragma unroll
        for (int j = 0; j < 4; ++j) acc[i][j] = z4;

    // staging coords: o = p*4096 + tid*16 bytes; LDS row = o>>6 (64B rows), col byte = o&63
    int strow[2], stcol[2];
    #pragma unroll
    for (int p = 0; p < 2; ++p) {
        int o = p * 4096 + tid * 16;
        strow[p] = o >> 6;
        stcol[p] = o & 63;
    }

    for (int k0 = 0; k0 < 1024; k0 += 32) {
        __syncthreads();
        #pragma unroll
        for (int p = 0; p < 2; ++p) {
            int o = p * 4096 + tid * 16;
            gload16((const char*)(A  + (size_t)(bm + strow[p]) * 1024 + k0) + stcol[p],
                    (char*)&Als[0][0] + o);
            gload16((const char*)(WT + (size_t)(bn + strow[p]) * 1024 + k0) + stcol[p],
                    (char*)&Bls[0][0] + o);
        }
        __syncthreads();   // compiler drains vmcnt(0) before s_barrier -> tiles ready

        bf8_t af[4], bfv[4];
        #pragma unroll
        for (int i = 0; i < 4; ++i) af[i]  = *(const bf8_t*)(&Als[wr * 64 + i * 16 + lr][lg * 8]);
        #pragma unroll
        for (int j = 0; j < 4; ++j) bfv[j] = *(const bf8_t*)(&Bls[wc * 64 + j * 16 + lr][lg * 8]);
        #pragma unroll
        for (int i = 0; i < 4; ++i)
            #pragma unroll
            for (int j = 0; j < 4; ++j)
                acc[i][j] = MFMA16(af[i], bfv[j], acc[i][j]);
    }

    if (MODE == 0) {
        unsigned short* O = (unsigned short*)outp + (size_t)blockIdx.z * (8192 * 1024);
        const float* bias = (blockIdx.z == 0) ? b0 : (blockIdx.z == 1) ? b1 : b2;
        const float sc = (blockIdx.z == 0) ? 0.18033688011112042f : 1.0f; // 0.125*log2(e)
        #pragma unroll
        for (int i = 0; i < 4; ++i)
            #pragma unroll
            for (int j = 0; j < 4; ++j)
                #pragma unroll
                for (int r = 0; r < 4; ++r) {
                    int row = bm + wr * 64 + i * 16 + lg * 4 + r;
                    int col = bn + wc * 64 + j * 16 + lr;
                    float v = (acc[i][j][r] + bias[col]) * sc;
                    int b = row >> 11, s = row & 2047, h = col >> 6, d = col & 63;
                    O[(((size_t)(b * 16 + h)) * 2048 + s) * 64 + d] = f2bf(v);
                }
    } else {
        float* O = (float*)outp;
        #pragma unroll
        for (int i = 0; i < 4; ++i)
            #pragma unroll
            for (int j = 0; j < 4; ++j)
                #pragma unroll
                for (int r = 0; r < 4; ++r) {
                    int row = bm + wr * 64 + i * 16 + lg * 4 + r;
                    int col = bn + wc * 64 + j * 16 + lr;
                    O[(size_t)row * 1024 + col] = acc[i][j][r] + b0[col];
                }
    }
}

// ---------- V [bh][s][d] -> VT [bh][d][s] ----------
__global__ __launch_bounds__(256) void k_vtrans(const unsigned short* __restrict__ V,
                                                unsigned short* __restrict__ VT) {
    __shared__ unsigned short t[64][72];
    const int bh = blockIdx.y;
    const int s0 = blockIdx.x * 64;
    const int tid = threadIdx.x;
    const int sr = tid >> 2;
    const int c0 = (tid & 3) * 16;
    const unsigned short* src = V + ((size_t)bh * 2048 + s0 + sr) * 64 + c0;
    bf8_t a = *(const bf8_t*)src;
    bf8_t bq = *(const bf8_t*)(src + 8);
    #pragma unroll
    for (int e = 0; e < 8; ++e) {
        t[c0 + e][sr]     = (unsigned short)a[e];
        t[c0 + 8 + e][sr] = (unsigned short)bq[e];
    }
    __syncthreads();
    unsigned short* dst = VT + ((size_t)bh * 64 + sr) * 2048 + s0 + c0;
    *(bf8_t*)dst       = *(const bf8_t*)&t[sr][c0];
    *(bf8_t*)(dst + 8) = *(const bf8_t*)&t[sr][c0 + 8];
}

// ---------- flash attention: LDS-staged K/V (dbuf, gload_lds, XOR-swizzle) ----------
// grid 1024: 16 q-tiles x 64 heads, XCD-grouped. 4 waves x 32 q-rows (2 subtiles).
__global__ __launch_bounds__(256) void k_attn(
    const unsigned short* __restrict__ Q,    // [64][2048][64], pre-scaled by 0.125*log2e
    const unsigned short* __restrict__ K,    // [64][2048][64]
    const unsigned short* __restrict__ VT,   // [64][64][2048]
    const float* __restrict__ fbias,         // [4][2048] 0/-1e30
    unsigned short* __restrict__ O)          // [8192][1024]
{
    __shared__ __align__(16) unsigned short Kls[2][64][64];  // [buf][key][d], XOR-swizzled
    __shared__ __align__(16) unsigned short Vls[2][64][64];  // [buf][d][key], XOR-swizzled
    __shared__ __align__(16) unsigned short pls[4][16][72];  // per-wave P roundtrip
    const int tid  = threadIdx.x;
    const int lane = tid & 63;
    const int w    = tid >> 6;
    const int lg   = lane >> 4, lr = lane & 15;
    const int lg4  = lg * 4;

    const int id = blockIdx.x;
    const int bh = (id & 7) * 8 + ((id >> 3) & 7);   // XCD (id&7) owns 8 heads -> 4MB L2 set
    const int qt = id >> 6;                           // 0..15
    const int b  = bh >> 4, h = bh & 15;
    const int q0 = qt * 128 + w * 32;
    const size_t base = (size_t)bh * (2048 * 64);

    const char* Kbase = (const char*)(K + base);
    const char* Vbase = (const char*)(VT + (size_t)bh * (64 * 2048));

    // staging coords: LDS byte o = p*4096 + tid*16; row = o>>7 (128B rows), col = o&127.
    // LDS[o] must hold tile[row][col ^ ((row&7)<<4)] so swizzled reads return linear data.
    int srow[2], scol[2];
    #pragma unroll
    for (int p = 0; p < 2; ++p) {
        int o = p * 4096 + tid * 16;
        srow[p] = o >> 7;
        scol[p] = (o & 127) ^ ((srow[p] & 7) << 4);
    }

    auto stage = [&](int buf, int k0) {
        #pragma unroll
        for (int p = 0; p < 2; ++p) {
            int o = p * 4096 + tid * 16;
            gload16(Kbase + (size_t)(k0 + srow[p]) * 128 + scol[p],
                    (char*)&Kls[buf][0][0] + o);
            gload16(Vbase + (size_t)srow[p] * 4096 + (size_t)k0 * 2 + scol[p],
                    (char*)&Vls[buf][0][0] + o);
        }
    };

    // Q fragments, 2 subtiles (B-operand: lane holds Q[q=lr][dh=lg*8..])
    bf8_t qf[2][2];
    #pragma unroll
    for (int sub = 0; sub < 2; ++sub) {
        const unsigned short* qp = Q + base + (size_t)(q0 + sub * 16 + lr) * 64 + lg * 8;
        qf[sub][0] = *(const bf8_t*)qp;
        qf[sub][1] = *(const bf8_t*)(qp + 32);
    }

    const f4_t z4 = {0.f, 0.f, 0.f, 0.f};
    f4_t oacc[2][4];
    #pragma unroll
    for (int sub = 0; sub < 2; ++sub)
        #pragma unroll
        for (int nf = 0; nf < 4; ++nf) oacc[sub][nf] = z4;
    float mrow[2] = {-1e30f, -1e30f};
    float lsum[2] = {0.f, 0.f};

    const float* fb = fbias + b * 2048 + lg4;
    unsigned short* pw = &pls[w][lr][0];
    const char* pr = (const char*)&pls[w][lr][0];
    const int sw = (lr & 7) << 4;

    bf8_t vfr[4][2];   // V fragments, shared by both subtiles

    auto sm_pv = [&](f4_t (&s)[4], float& mr, float& ls, f4_t (&oa)[4]) {
        float m0 = fmaxf(fmaxf(s[0][0], s[0][1]), fmaxf(s[0][2], s[0][3]));
        float m1 = fmaxf(fmaxf(s[1][0], s[1][1]), fmaxf(s[1][2], s[1][3]));
        float m2 = fmaxf(fmaxf(s[2][0], s[2][1]), fmaxf(s[2][2], s[2][3]));
        float m3 = fmaxf(fmaxf(s[3][0], s[3][1]), fmaxf(s[3][2], s[3][3]));
        float smax = fmaxf(fmaxf(m0, m1), fmaxf(m2, m3));
        smax = fmaxf(smax, __shfl_xor(smax, 16));
        smax = fmaxf(smax, __shfl_xor(smax, 32));
        if (__any(smax > mr)) {                       // defer-max rescale
            float mnew = fmaxf(mr, smax);
            float c = EXP2(mr - mnew);
            mr = mnew;
            ls *= c;
            #pragma unroll
            for (int r = 0; r < 4; ++r) {
                float cr = __shfl(c, lg4 + r);
                oa[0][r] *= cr; oa[1][r] *= cr; oa[2][r] *= cr; oa[3][r] *= cr;
            }
        }
        float bsum = 0.0f;
        #pragma unroll
        for (int mf = 0; mf < 4; ++mf) {
            float p0 = EXP2(s[mf][0] - mr);
            float p1 = EXP2(s[mf][1] - mr);
            float p2 = EXP2(s[mf][2] - mr);
            float p3 = EXP2(s[mf][3] - mr);
            bsum += (p0 + p1) + (p2 + p3);
            ushort4 pk;
            pk.x = f2bf(p0); pk.y = f2bf(p1); pk.z = f2bf(p2); pk.w = f2bf(p3);
            *(ushort4*)(pw + mf * 16 + lg4) = pk;
        }
        bsum += __shfl_xor(bsum, 16);
        bsum += __shfl_xor(bsum, 32);
        ls += bsum;
        bf8_t pa0 = *(const bf8_t*)(pr + lg * 16);
        bf8_t pa1 = *(const bf8_t*)(pr + 64 + lg * 16);
        #pragma unroll
        for (int nf = 0; nf < 4; ++nf) {
            oa[nf] = MFMA16(pa0, vfr[nf][0], oa[nf]);
            oa[nf] = MFMA16(pa1, vfr[nf][1], oa[nf]);
        }
    };

    stage(0, 0);
    __syncthreads();

    for (int t = 0; t < 32; ++t) {
        const int cur = t & 1;
        if (t < 31) stage(cur ^ 1, (t + 1) * 64);     // async prefetch into other buffer
        const int k0 = t * 64;

        // fragments from LDS (swizzled reads)
        bf8_t kf[4][2];
        #pragma unroll
        for (int mf = 0; mf < 4; ++mf) {
            const char* kr = (const char*)&Kls[cur][mf * 16 + lr][0];
            kf[mf][0] = *(const bf8_t*)(kr + ((lg * 16) ^ sw));
            kf[mf][1] = *(const bf8_t*)(kr + ((64 + lg * 16) ^ sw));
            const char* vr = (const char*)&Vls[cur][mf * 16 + lr][0];
            vfr[mf][0] = *(const bf8_t*)(vr + ((lg * 16) ^ sw));
            vfr[mf][1] = *(const bf8_t*)(vr + ((64 + lg * 16) ^ sw));
        }

        // S^T = K·Q^T for both subtiles: lane holds S[key=lg4+r][q=lr]
        f4_t s0[4], s1[4];
        #pragma unroll
        for (int mf = 0; mf < 4; ++mf) {
            f4_t a0 = MFMA16(kf[mf][0], qf[0][0], z4);
            s0[mf]  = MFMA16(kf[mf][1], qf[0][1], a0);
            f4_t a1 = MFMA16(kf[mf][0], qf[1][0], z4);
            s1[mf]  = MFMA16(kf[mf][1], qf[1][1], a1);
        }
        // additive key mask (global, L1/L2-hot, shared by both subtiles)
        #pragma unroll
        for (int mf = 0; mf < 4; ++mf) {
            float4 bv = *(const float4*)(fb + k0 + mf * 16);
            s0[mf][0] += bv.x; s0[mf][1] += bv.y; s0[mf][2] += bv.z; s0[mf][3] += bv.w;
            s1[mf][0] += bv.x; s1[mf][1] += bv.y; s1[mf][2] += bv.z; s1[mf][3] += bv.w;
        }

        sm_pv(s0, mrow[0], lsum[0], oacc[0]);
        sm_pv(s1, mrow[1], lsum[1], oacc[1]);

        __syncthreads();   // drains vmcnt(0): prefetch landed; all waves done with cur buf
    }

    // normalize + write [B,S,D] bf16
    #pragma unroll
    for (int sub = 0; sub < 2; ++sub)
        #pragma unroll
        for (int r = 0; r < 4; ++r) {
            float ls = __shfl(lsum[sub], lg4 + r);
            float inv = 1.0f / ls;
            int srw = q0 + sub * 16 + lg4 + r;
            size_t ob = ((size_t)(b * 2048 + srw)) * 1024 + h * 64;
            #pragma unroll
            for (int nf = 0; nf < 4; ++nf)
                O[ob + nf * 16 + lr] = f2bf(oacc[sub][nf][r] * inv);
        }
}

// ---------- launch ----------
extern "C" void kernel_launch(void* const* d_in, const int* in_sizes, int n_in,
                              void* d_out, int out_size, void* d_ws, size_t ws_size,
                              hipStream_t stream) {
    const float* x  = (const float*)d_in[0];
    const void*  mask = d_in[1];
    const float* Wq = (const float*)d_in[2];
    const float* bq = (const float*)d_in[3];
    const float* Wk = (const float*)d_in[4];
    const float* bk = (const float*)d_in[5];
    const float* Wv = (const float*)d_in[6];
    const float* bv = (const float*)d_in[7];
    const float* Wo = (const float*)d_in[8];
    const float* bo = (const float*)d_in[9];

    char* ws = (char*)d_ws;
    float*          fbias = (float*)(ws + 1024);
    unsigned short* xb    = (unsigned short*)(ws + 65536);                // 16 MiB (reused as VT)
    unsigned short* wT    = (unsigned short*)(ws + 65536 + 16777216);     // 8 MiB
    unsigned short* qkv   = (unsigned short*)(ws + 65536 + 25165824);     // 48 MiB
    unsigned short* attnb = (unsigned short*)(ws + 65536 + 75497472);     // 16 MiB

    unsigned short* Qb = qkv;
    unsigned short* Kb = qkv + 8388608;
    unsigned short* Vb = qkv + 16777216;
    unsigned short* VT = xb;   // xb dead after QKV GEMM

    k_bias<<<1, 1024, 0, stream>>>(mask, fbias);
    k_cvt<<<8192, 256, 0, stream>>>(x, xb, 2097152);
    k_transw<<<dim3(32, 32, 4), dim3(32, 8), 0, stream>>>(Wq, Wk, Wv, Wo, wT);
    k_gemm<0><<<dim3(8, 64, 3), 256, 0, stream>>>(xb, wT, bq, bk, bv, (void*)qkv);
    k_vtrans<<<dim3(32, 64), 256, 0, stream>>>(Vb, VT);
    k_attn<<<1024, 256, 0, stream>>>(Qb, Kb, VT, fbias, attnb);
    k_gemm<1><<<dim3(8, 64, 1), 256, 0, stream>>>(attnb, wT + 3145728, bo, bo, bo, d_out);
}

// Round 6
// 263.593 us; speedup vs baseline: 2.3069x; 1.0723x over previous
//
#include <hip/hip_runtime.h>
#include <hip/hip_bf16.h>

// ---------- types ----------
typedef __attribute__((ext_vector_type(8))) short bf8_t;   // 8 bf16 (4 VGPRs)
typedef __attribute__((ext_vector_type(4))) short bf4_t;   // 4 bf16 (2 VGPRs)
typedef __attribute__((ext_vector_type(4))) float f4_t;    // MFMA accumulator
typedef __attribute__((ext_vector_type(2))) unsigned int u2_t;

#define MFMA16(a, b, c) __builtin_amdgcn_mfma_f32_16x16x32_bf16((a), (b), (c), 0, 0, 0)

// K=16 bf16 MFMA: B-operand layout B[col=lane&15][k=(lane>>4)*4+e] matches the
// in-register P layout produced by swapped QK^T -> PV needs NO LDS roundtrip.
static __device__ inline f4_t mfma_k16(bf4_t a, bf4_t b, f4_t c) {
#if __has_builtin(__builtin_amdgcn_mfma_f32_16x16x16bf16_1k)
    return __builtin_amdgcn_mfma_f32_16x16x16bf16_1k(a, b, c, 0, 0, 0);
#else
    bf8_t a8 = {a[0], a[1], a[2], a[3], (short)0, (short)0, (short)0, (short)0};
    bf8_t b8 = {b[0], b[1], b[2], b[3], (short)0, (short)0, (short)0, (short)0};
    return MFMA16(a8, b8, c);
#endif
}

#if __has_builtin(__builtin_amdgcn_exp2f)
#define EXP2(x) __builtin_amdgcn_exp2f(x)
#else
#define EXP2(x) exp2f(x)
#endif

static __device__ inline unsigned short f2bf(float f) {
    unsigned int u = __float_as_uint(f);
    unsigned int r = 0x7fffu + ((u >> 16) & 1u);
    return (unsigned short)((u + r) >> 16);
}

// pack 2 fp32 -> 2 bf16 in one u32 (T12 primitive; no builtin on gfx950)
static __device__ inline unsigned int cvtpk_bf16(float lo, float hi) {
    unsigned int r;
    asm("v_cvt_pk_bf16_f32 %0, %1, %2" : "=v"(r) : "v"(lo), "v"(hi));
    return r;
}

// async global->LDS, 16B per lane; dest = wave-uniform base + lane*16
static __device__ inline void gload16(const void* g, void* l) {
    __builtin_amdgcn_global_load_lds(
        (const __attribute__((address_space(1))) unsigned int*)g,
        (__attribute__((address_space(3))) unsigned int*)l, 16, 0, 0);
}

// ---------- mask probe + additive-bias build ----------
__global__ void k_bias(const void* __restrict__ maskp, float* __restrict__ fbias) {
    __shared__ int s_int, s_flt;
    const unsigned int* mw = (const unsigned int*)maskp;
    if (threadIdx.x == 0) { s_int = 1; s_flt = 1; }
    __syncthreads();
    int li = 1, lf = 1;
    for (int i = threadIdx.x; i < 2048; i += 1024) {
        unsigned int v = mw[i];
        if (v != 0u && v != 1u) li = 0;
        if (v != 0u && v != 0x3F800000u) lf = 0;
    }
    if (!li) atomicAnd(&s_int, 0);
    if (!lf) atomicAnd(&s_flt, 0);
    __syncthreads();
    const int flag = s_int ? 0 : (s_flt ? 1 : 2);
    const int*           mi = (const int*)maskp;
    const float*         mf = (const float*)maskp;
    const unsigned char* mb = (const unsigned char*)maskp;
    for (int i = threadIdx.x; i < 8192; i += 1024) {
        bool m = (flag == 0) ? (mi[i] != 0) : (flag == 1) ? (mf[i] != 0.0f) : (mb[i] != 0);
        fbias[i] = m ? -1e30f : 0.0f;
    }
}

// ---------- fp32 -> bf16 convert (x) ----------
__global__ void k_cvt(const float* __restrict__ x, unsigned short* __restrict__ xb, int n4) {
    int i = blockIdx.x * blockDim.x + threadIdx.x;
    if (i < n4) {
        float4 v = ((const float4*)x)[i];
        ushort4 o;
        o.x = f2bf(v.x); o.y = f2bf(v.y); o.z = f2bf(v.z); o.w = f2bf(v.w);
        ((ushort4*)xb)[i] = o;
    }
}

// ---------- W [K][N] fp32 -> WT [N][K] bf16 (4 matrices) ----------
__global__ void k_transw(const float* __restrict__ Wq, const float* __restrict__ Wk,
                         const float* __restrict__ Wv, const float* __restrict__ Wo,
                         unsigned short* __restrict__ WT) {
    __shared__ float tile[32][33];
    const float* W = (blockIdx.z == 0) ? Wq : (blockIdx.z == 1) ? Wk : (blockIdx.z == 2) ? Wv : Wo;
    unsigned short* out = WT + (size_t)blockIdx.z * 1024 * 1024;
    int n_r = blockIdx.x * 32 + threadIdx.x;
    int k_r = blockIdx.y * 32 + threadIdx.y;
    #pragma unroll
    for (int j = 0; j < 32; j += 8)
        tile[threadIdx.y + j][threadIdx.x] = W[(size_t)(k_r + j) * 1024 + n_r];
    __syncthreads();
    int k_w = blockIdx.y * 32 + threadIdx.x;
    int n_w = blockIdx.x * 32 + threadIdx.y;
    #pragma unroll
    for (int j = 0; j < 32; j += 8)
        out[(size_t)(n_w + j) * 1024 + k_w] = f2bf(tile[threadIdx.x][threadIdx.y + j]);
}

// ---------- GEMM: C[8192][1024] = A_bf16 @ WT^T (+bias) ----------
// Double-buffered gload_lds staging (T3-minimum: stage(t+1) before compute(t)).
// MODE 0: z=0 -> Q bf16 [bh][s][dh] scaled by 0.125*log2e; z=1 -> K same layout;
//         z=2 -> V^T bf16 [bh][dh][s] (outp2), eliminating the k_vtrans pass.
// MODE 1: fp32 out [M][N] + bias.
template <int MODE>
__global__ __launch_bounds__(256) void k_gemm(
    const unsigned short* __restrict__ A,
    const unsigned short* __restrict__ WTb,
    const float* __restrict__ b0, const float* __restrict__ b1, const float* __restrict__ b2,
    void* __restrict__ outp, void* __restrict__ outp2)
{
    __shared__ __align__(16) unsigned short Als[2][128][32];
    __shared__ __align__(16) unsigned short Bls[2][128][32];
    const int tid  = threadIdx.x;
    const int lane = tid & 63;
    const int w    = tid >> 6;
    const int wr   = w >> 1, wc = w & 1;
    const int lg   = lane >> 4, lr = lane & 15;
    const int bm   = blockIdx.y * 128;
    const int bn   = blockIdx.x * 128;
    const unsigned short* WT = WTb + (MODE == 0 ? (size_t)blockIdx.z * (1024 * 1024) : 0);

    f4_t acc[4][4];
    const f4_t z4 = {0.f, 0.f, 0.f, 0.f};
    #pragma unroll
    for (int i = 0; i < 4; ++i)
        #pragma unroll
        for (int j = 0; j < 4; ++j) acc[i][j] = z4;

    int strow[2], stcol[2];
    #pragma unroll
    for (int p = 0; p < 2; ++p) {
        int o = p * 4096 + tid * 16;
        strow[p] = o >> 6;
        stcol[p] = o & 63;
    }

    auto stage = [&](int buf, int k0) {
        #pragma unroll
        for (int p = 0; p < 2; ++p) {
            int o = p * 4096 + tid * 16;
            gload16((const char*)(A  + (size_t)(bm + strow[p]) * 1024 + k0) + stcol[p],
                    (char*)&Als[buf][0][0] + o);
            gload16((const char*)(WT + (size_t)(bn + strow[p]) * 1024 + k0) + stcol[p],
                    (char*)&Bls[buf][0][0] + o);
        }
    };

    stage(0, 0);
    __syncthreads();

    for (int k0 = 0; k0 < 1024; k0 += 32) {
        const int buf = (k0 >> 5) & 1;
        if (k0 + 32 < 1024) stage(buf ^ 1, k0 + 32);   // overlap with compute

        bf8_t af[4], bfv[4];
        #pragma unroll
        for (int i = 0; i < 4; ++i) af[i]  = *(const bf8_t*)(&Als[buf][wr * 64 + i * 16 + lr][lg * 8]);
        #pragma unroll
        for (int j = 0; j < 4; ++j) bfv[j] = *(const bf8_t*)(&Bls[buf][wc * 64 + j * 16 + lr][lg * 8]);
        __builtin_amdgcn_s_setprio(1);
        #pragma unroll
        for (int i = 0; i < 4; ++i)
            #pragma unroll
            for (int j = 0; j < 4; ++j)
                acc[i][j] = MFMA16(af[i], bfv[j], acc[i][j]);
        __builtin_amdgcn_s_setprio(0);

        __syncthreads();   // drains vmcnt(0): next buf staged; all waves done with buf
    }

    if (MODE == 0) {
        const float* bias = (blockIdx.z == 0) ? b0 : (blockIdx.z == 1) ? b1 : b2;
        const float sc = (blockIdx.z == 0) ? 0.18033688011112042f : 1.0f; // 0.125*log2(e)
        if (blockIdx.z < 2) {
            unsigned short* O = (unsigned short*)outp + (size_t)blockIdx.z * (8192 * 1024);
            #pragma unroll
            for (int i = 0; i < 4; ++i)
                #pragma unroll
                for (int j = 0; j < 4; ++j)
                    #pragma unroll
                    for (int r = 0; r < 4; ++r) {
                        int row = bm + wr * 64 + i * 16 + lg * 4 + r;
                        int col = bn + wc * 64 + j * 16 + lr;
                        float v = (acc[i][j][r] + bias[col]) * sc;
                        int b = row >> 11, s = row & 2047, h = col >> 6, d = col & 63;
                        O[(((size_t)(b * 16 + h)) * 2048 + s) * 64 + d] = f2bf(v);
                    }
        } else {
            // V^T: [bh][dh][s]
            unsigned short* OT = (unsigned short*)outp2;
            #pragma unroll
            for (int i = 0; i < 4; ++i)
                #pragma unroll
                for (int j = 0; j < 4; ++j)
                    #pragma unroll
                    for (int r = 0; r < 4; ++r) {
                        int row = bm + wr * 64 + i * 16 + lg * 4 + r;
                        int col = bn + wc * 64 + j * 16 + lr;
                        float v = acc[i][j][r] + bias[col];
                        int b = row >> 11, s = row & 2047, h = col >> 6, d = col & 63;
                        OT[(((size_t)(b * 16 + h)) * 64 + d) * 2048 + s] = f2bf(v);
                    }
        }
    } else {
        float* O = (float*)outp;
        #pragma unroll
        for (int i = 0; i < 4; ++i)
            #pragma unroll
            for (int j = 0; j < 4; ++j)
                #pragma unroll
                for (int r = 0; r < 4; ++r) {
                    int row = bm + wr * 64 + i * 16 + lg * 4 + r;
                    int col = bn + wc * 64 + j * 16 + lr;
                    O[(size_t)row * 1024 + col] = acc[i][j][r] + b0[col];
                }
    }
}

// ---------- flash attention: LDS K/V dbuf + fully in-register softmax/P ----------
// grid 1024: 16 q-tiles x 64 heads, XCD-grouped. 4 waves x 32 q-rows (2 subtiles).
// P stays in registers: swapped QK^T output == B-operand of mfma 16x16x16 (K=16 chunks).
// Accumulator is O^T[d][q]: each lane owns one q-row -> scalar rescale, no shuffles.
__global__ __launch_bounds__(256) void k_attn(
    const unsigned short* __restrict__ Q,    // [64][2048][64], pre-scaled by 0.125*log2e
    const unsigned short* __restrict__ K,    // [64][2048][64]
    const unsigned short* __restrict__ VT,   // [64][64][2048]
    const float* __restrict__ fbias,         // [4][2048] 0/-1e30
    unsigned short* __restrict__ O)          // [8192][1024]
{
    __shared__ __align__(16) unsigned short Kls[2][64][64];  // [buf][key][d], XOR-swizzled
    __shared__ __align__(16) unsigned short Vls[2][64][64];  // [buf][d][key], XOR-swizzled
    const int tid  = threadIdx.x;
    const int lane = tid & 63;
    const int w    = tid >> 6;
    const int lg   = lane >> 4, lr = lane & 15;
    const int lg4  = lg * 4;

    const int id = blockIdx.x;
    const int bh = (id & 7) * 8 + ((id >> 3) & 7);   // XCD (id&7) owns 8 heads
    const int qt = id >> 6;                           // 0..15
    const int b  = bh >> 4, h = bh & 15;
    const int q0 = qt * 128 + w * 32;
    const size_t base = (size_t)bh * (2048 * 64);

    const char* Kbase = (const char*)(K + base);
    const char* Vbase = (const char*)(VT + (size_t)bh * (64 * 2048));

    int srow[2], scol[2];
    #pragma unroll
    for (int p = 0; p < 2; ++p) {
        int o = p * 4096 + tid * 16;
        srow[p] = o >> 7;
        scol[p] = (o & 127) ^ ((srow[p] & 7) << 4);   // inverse swizzle on global src
    }

    auto stage = [&](int buf, int k0) {
        #pragma unroll
        for (int p = 0; p < 2; ++p) {
            int o = p * 4096 + tid * 16;
            gload16(Kbase + (size_t)(k0 + srow[p]) * 128 + scol[p],
                    (char*)&Kls[buf][0][0] + o);
            gload16(Vbase + (size_t)srow[p] * 4096 + (size_t)k0 * 2 + scol[p],
                    (char*)&Vls[buf][0][0] + o);
        }
    };

    // Q fragments, 2 subtiles (B-operand: lane holds Q[q=lr][dh=lg*8..])
    bf8_t qf[2][2];
    #pragma unroll
    for (int sub = 0; sub < 2; ++sub) {
        const unsigned short* qp = Q + base + (size_t)(q0 + sub * 16 + lr) * 64 + lg * 8;
        qf[sub][0] = *(const bf8_t*)qp;
        qf[sub][1] = *(const bf8_t*)(qp + 32);
    }

    const f4_t z4 = {0.f, 0.f, 0.f, 0.f};
    f4_t oacc[2][4];                 // [sub][nf]: O^T[d=nf*16+lg4+r][q=lr]
    #pragma unroll
    for (int sub = 0; sub < 2; ++sub)
        #pragma unroll
        for (int nf = 0; nf < 4; ++nf) oacc[sub][nf] = z4;
    float mrow[2] = {-1e28f, -1e28f};   // > masked (-1e30): all-masked prefix stays zero
    float lsum[2] = {0.f, 0.f};         // per-lane partials; reduced once at the end

    const float* fb = fbias + b * 2048 + lg4;
    const int sw = (lr & 7) << 4;
    const int cA = (lg * 16) ^ sw;
    const int cB = (64 + lg * 16) ^ sw;
    int vcol[4];
    #pragma unroll
    for (int mf = 0; mf < 4; ++mf) vcol[mf] = (32 * mf + 8 * lg) ^ sw;

    // softmax on 16 in-register scores -> packed bf16 P fragments (B-operand, K=16)
    auto sm = [&](f4_t (&s)[4], float& mr, float& ls, f4_t (&oa)[4], bf4_t (&pf)[4]) {
        float m0 = fmaxf(fmaxf(s[0][0], s[0][1]), fmaxf(s[0][2], s[0][3]));
        float m1 = fmaxf(fmaxf(s[1][0], s[1][1]), fmaxf(s[1][2], s[1][3]));
        float m2 = fmaxf(fmaxf(s[2][0], s[2][1]), fmaxf(s[2][2], s[2][3]));
        float m3 = fmaxf(fmaxf(s[3][0], s[3][1]), fmaxf(s[3][2], s[3][3]));
        float smax = fmaxf(fmaxf(m0, m1), fmaxf(m2, m3));
        smax = fmaxf(smax, __shfl_xor(smax, 16));
        smax = fmaxf(smax, __shfl_xor(smax, 32));
        if (__any(smax > mr + 6.0f)) {          // defer-max (T13, THR=6 -> P <= 64)
            float mnew = fmaxf(mr, smax);
            float c = EXP2(mr - mnew);
            mr = mnew;
            ls *= c;
            #pragma unroll
            for (int nf = 0; nf < 4; ++nf) oa[nf] *= c;   // lane owns q=lr: scalar mul
        }
        #pragma unroll
        for (int mf = 0; mf < 4; ++mf) {
            float p0 = EXP2(s[mf][0] - mr);
            float p1 = EXP2(s[mf][1] - mr);
            float p2 = EXP2(s[mf][2] - mr);
            float p3 = EXP2(s[mf][3] - mr);
            ls += (p0 + p1) + (p2 + p3);
            u2_t u;
            u.x = cvtpk_bf16(p0, p1);
            u.y = cvtpk_bf16(p2, p3);
            pf[mf] = __builtin_bit_cast(bf4_t, u);
        }
    };

    stage(0, 0);
    __syncthreads();

    for (int t = 0; t < 32; ++t) {
        const int cur = t & 1;
        if (t < 31) stage(cur ^ 1, (t + 1) * 64);    // async prefetch into other buffer
        const int k0 = t * 64;

        // K fragments (swizzled LDS reads)
        bf8_t kf[4][2];
        #pragma unroll
        for (int mf = 0; mf < 4; ++mf) {
            const char* kr = (const char*)&Kls[cur][mf * 16 + lr][0];
            kf[mf][0] = *(const bf8_t*)(kr + cA);
            kf[mf][1] = *(const bf8_t*)(kr + cB);
        }

        // S^T = K·Q^T: lane holds S[key=16mf+lg4+r][q=lr]
        f4_t s0[4], s1[4];
        __builtin_amdgcn_s_setprio(1);
        #pragma unroll
        for (int mf = 0; mf < 4; ++mf) {
            s0[mf] = MFMA16(kf[mf][1], qf[0][1], MFMA16(kf[mf][0], qf[0][0], z4));
            s1[mf] = MFMA16(kf[mf][1], qf[1][1], MFMA16(kf[mf][0], qf[1][0], z4));
        }
        __builtin_amdgcn_s_setprio(0);

        // V^T A-fragments early: ds latency hides under softmax VALU
        bf4_t vfrag[4][4];   // [nf][mf] = V^T[d=nf*16+lr][key=16mf+lg4 ..+3]
        #pragma unroll
        for (int nf = 0; nf < 4; ++nf) {
            const char* vr = (const char*)&Vls[cur][nf * 16 + lr][0];
            #pragma unroll
            for (int mf = 0; mf < 4; ++mf)
                vfrag[nf][mf] = *(const bf4_t*)(vr + vcol[mf]);
        }

        // additive key mask (shared by both subtiles)
        #pragma unroll
        for (int mf = 0; mf < 4; ++mf) {
            float4 bv = *(const float4*)(fb + k0 + mf * 16);
            s0[mf][0] += bv.x; s0[mf][1] += bv.y; s0[mf][2] += bv.z; s0[mf][3] += bv.w;
            s1[mf][0] += bv.x; s1[mf][1] += bv.y; s1[mf][2] += bv.z; s1[mf][3] += bv.w;
        }

        bf4_t pf0[4], pf1[4];
        sm(s0, mrow[0], lsum[0], oacc[0], pf0);
        sm(s1, mrow[1], lsum[1], oacc[1], pf1);

        // PV in registers: O^T[d][q] += V^T_chunk · P_chunk  (16-key chunks)
        __builtin_amdgcn_s_setprio(1);
        #pragma unroll
        for (int nf = 0; nf < 4; ++nf)
            #pragma unroll
            for (int mf = 0; mf < 4; ++mf)
                oacc[0][nf] = mfma_k16(vfrag[nf][mf], pf0[mf], oacc[0][nf]);
        #pragma unroll
        for (int nf = 0; nf < 4; ++nf)
            #pragma unroll
            for (int mf = 0; mf < 4; ++mf)
                oacc[1][nf] = mfma_k16(vfrag[nf][mf], pf1[mf], oacc[1][nf]);
        __builtin_amdgcn_s_setprio(0);

        __syncthreads();   // drains vmcnt(0): prefetch landed; all waves done with cur
    }

    // normalize + write [B,S,D] bf16 (lane owns q=lr, d=nf*16+lg4+0..3 -> ushort4)
    #pragma unroll
    for (int sub = 0; sub < 2; ++sub) {
        float lt = lsum[sub];
        lt += __shfl_xor(lt, 16);
        lt += __shfl_xor(lt, 32);
        float inv = 1.0f / lt;
        int qrow = q0 + sub * 16 + lr;
        size_t ob = ((size_t)(b * 2048 + qrow)) * 1024 + h * 64 + lg4;
        #pragma unroll
        for (int nf = 0; nf < 4; ++nf) {
            ushort4 o4;
            o4.x = f2bf(oacc[sub][nf][0] * inv);
            o4.y = f2bf(oacc[sub][nf][1] * inv);
            o4.z = f2bf(oacc[sub][nf][2] * inv);
            o4.w = f2bf(oacc[sub][nf][3] * inv);
            *(ushort4*)(O + ob + nf * 16) = o4;
        }
    }
}

// ---------- launch ----------
extern "C" void kernel_launch(void* const* d_in, const int* in_sizes, int n_in,
                              void* d_out, int out_size, void* d_ws, size_t ws_size,
                              hipStream_t stream) {
    const float* x  = (const float*)d_in[0];
    const void*  mask = d_in[1];
    const float* Wq = (const float*)d_in[2];
    const float* bq = (const float*)d_in[3];
    const float* Wk = (const float*)d_in[4];
    const float* bk = (const float*)d_in[5];
    const float* Wv = (const float*)d_in[6];
    const float* bv = (const float*)d_in[7];
    const float* Wo = (const float*)d_in[8];
    const float* bo = (const float*)d_in[9];

    char* ws = (char*)d_ws;
    float*          fbias = (float*)(ws + 1024);
    unsigned short* xb    = (unsigned short*)(ws + 65536);                // 16 MiB
    unsigned short* wT    = (unsigned short*)(ws + 65536 + 16777216);     // 8 MiB
    unsigned short* qkv   = (unsigned short*)(ws + 65536 + 25165824);     // 48 MiB (Q,K,VT)
    unsigned short* attnb = (unsigned short*)(ws + 65536 + 75497472);     // 16 MiB

    unsigned short* Qb = qkv;
    unsigned short* Kb = qkv + 8388608;
    unsigned short* VT = qkv + 16777216;   // written directly by GEMM z==2 epilogue

    k_bias<<<1, 1024, 0, stream>>>(mask, fbias);
    k_cvt<<<8192, 256, 0, stream>>>(x, xb, 2097152);
    k_transw<<<dim3(32, 32, 4), dim3(32, 8), 0, stream>>>(Wq, Wk, Wv, Wo, wT);
    k_gemm<0><<<dim3(8, 64, 3), 256, 0, stream>>>(xb, wT, bq, bk, bv, (void*)qkv, (void*)VT);
    k_attn<<<1024, 256, 0, stream>>>(Qb, Kb, VT, fbias, attnb);
    k_gemm<1><<<dim3(8, 64, 1), 256, 0, stream>>>(attnb, wT + 3145728, bo, bo, bo, d_out, nullptr);
}

// Round 7
// 231.779 us; speedup vs baseline: 2.6235x; 1.1373x over previous
//
#include <hip/hip_runtime.h>
#include <hip/hip_bf16.h>

// ---------- types ----------
typedef __attribute__((ext_vector_type(8))) short bf8_t;   // 8 bf16 (4 VGPRs)
typedef __attribute__((ext_vector_type(4))) float f4_t;    // MFMA accumulator
typedef __attribute__((ext_vector_type(2))) unsigned int u2_t;
typedef __attribute__((ext_vector_type(4))) unsigned int u4_t;

#define MFMA16(a, b, c) __builtin_amdgcn_mfma_f32_16x16x32_bf16((a), (b), (c), 0, 0, 0)

#if __has_builtin(__builtin_amdgcn_exp2f)
#define EXP2(x) __builtin_amdgcn_exp2f(x)
#else
#define EXP2(x) exp2f(x)
#endif

static __device__ inline unsigned short f2bf(float f) {
    unsigned int u = __float_as_uint(f);
    unsigned int r = 0x7fffu + ((u >> 16) & 1u);
    return (unsigned short)((u + r) >> 16);
}

// pack 2 fp32 -> 2 bf16 in one u32 (T12 primitive; no builtin on gfx950)
static __device__ inline unsigned int cvtpk_bf16(float lo, float hi) {
    unsigned int r;
    asm("v_cvt_pk_bf16_f32 %0, %1, %2" : "=v"(r) : "v"(lo), "v"(hi));
    return r;
}

// async global->LDS, 16B per lane; dest = wave-uniform base + lane*16
static __device__ inline void gload16(const void* g, void* l) {
    __builtin_amdgcn_global_load_lds(
        (const __attribute__((address_space(1))) unsigned int*)g,
        (__attribute__((address_space(3))) unsigned int*)l, 16, 0, 0);
}

// ---------- mask probe + additive-bias build ----------
__global__ void k_bias(const void* __restrict__ maskp, float* __restrict__ fbias) {
    __shared__ int s_int, s_flt;
    const unsigned int* mw = (const unsigned int*)maskp;
    if (threadIdx.x == 0) { s_int = 1; s_flt = 1; }
    __syncthreads();
    int li = 1, lf = 1;
    for (int i = threadIdx.x; i < 2048; i += 1024) {
        unsigned int v = mw[i];
        if (v != 0u && v != 1u) li = 0;
        if (v != 0u && v != 0x3F800000u) lf = 0;
    }
    if (!li) atomicAnd(&s_int, 0);
    if (!lf) atomicAnd(&s_flt, 0);
    __syncthreads();
    const int flag = s_int ? 0 : (s_flt ? 1 : 2);
    const int*           mi = (const int*)maskp;
    const float*         mf = (const float*)maskp;
    const unsigned char* mb = (const unsigned char*)maskp;
    for (int i = threadIdx.x; i < 8192; i += 1024) {
        bool m = (flag == 0) ? (mi[i] != 0) : (flag == 1) ? (mf[i] != 0.0f) : (mb[i] != 0);
        fbias[i] = m ? -1e30f : 0.0f;
    }
}

// ---------- fp32 -> bf16 convert (x) ----------
__global__ void k_cvt(const float* __restrict__ x, unsigned short* __restrict__ xb, int n4) {
    int i = blockIdx.x * blockDim.x + threadIdx.x;
    if (i < n4) {
        float4 v = ((const float4*)x)[i];
        ushort4 o;
        o.x = f2bf(v.x); o.y = f2bf(v.y); o.z = f2bf(v.z); o.w = f2bf(v.w);
        ((ushort4*)xb)[i] = o;
    }
}

// ---------- W [K][N] fp32 -> WT [N][K] bf16 (4 matrices) ----------
__global__ void k_transw(const float* __restrict__ Wq, const float* __restrict__ Wk,
                         const float* __restrict__ Wv, const float* __restrict__ Wo,
                         unsigned short* __restrict__ WT) {
    __shared__ float tile[32][33];
    const float* W = (blockIdx.z == 0) ? Wq : (blockIdx.z == 1) ? Wk : (blockIdx.z == 2) ? Wv : Wo;
    unsigned short* out = WT + (size_t)blockIdx.z * 1024 * 1024;
    int n_r = blockIdx.x * 32 + threadIdx.x;
    int k_r = blockIdx.y * 32 + threadIdx.y;
    #pragma unroll
    for (int j = 0; j < 32; j += 8)
        tile[threadIdx.y + j][threadIdx.x] = W[(size_t)(k_r + j) * 1024 + n_r];
    __syncthreads();
    int k_w = blockIdx.y * 32 + threadIdx.x;
    int n_w = blockIdx.x * 32 + threadIdx.y;
    #pragma unroll
    for (int j = 0; j < 32; j += 8)
        out[(size_t)(n_w + j) * 1024 + k_w] = f2bf(tile[threadIdx.x][threadIdx.y + j]);
}

// ---------- GEMM: C[8192][1024] = A_bf16 @ WT^T (+bias) ----------
// MODE 0: z=0 -> Q bf16 [bh][s][dh] scaled by 0.125*log2e; z=1 -> K same layout;
//         z=2 -> V^T bf16 [bh][dh][s] with keys PERMUTED within each 64-block:
//                pos = 32*(mf>>1) + 8*lg + 4*(mf&1) + r for key = 16mf+4lg+r,
//                so k_attn's PV x32 A-fragments are contiguous 16B LDS reads.
// MODE 1: fp32 out [M][N] + bias.
template <int MODE>
__global__ __launch_bounds__(256) void k_gemm(
    const unsigned short* __restrict__ A,
    const unsigned short* __restrict__ WTb,
    const float* __restrict__ b0, const float* __restrict__ b1, const float* __restrict__ b2,
    void* __restrict__ outp, void* __restrict__ outp2)
{
    __shared__ __align__(16) unsigned short Als[2][128][32];
    __shared__ __align__(16) unsigned short Bls[2][128][32];
    const int tid  = threadIdx.x;
    const int lane = tid & 63;
    const int w    = tid >> 6;
    const int wr   = w >> 1, wc = w & 1;
    const int lg   = lane >> 4, lr = lane & 15;
    const int bm   = blockIdx.y * 128;
    const int bn   = blockIdx.x * 128;
    const unsigned short* WT = WTb + (MODE == 0 ? (size_t)blockIdx.z * (1024 * 1024) : 0);

    f4_t acc[4][4];
    const f4_t z4 = {0.f, 0.f, 0.f, 0.f};
    #pragma unroll
    for (int i = 0; i < 4; ++i)
        #pragma unroll
        for (int j = 0; j < 4; ++j) acc[i][j] = z4;

    int strow[2], stcol[2];
    #pragma unroll
    for (int p = 0; p < 2; ++p) {
        int o = p * 4096 + tid * 16;
        strow[p] = o >> 6;
        stcol[p] = o & 63;
    }

    auto stage = [&](int buf, int k0) {
        #pragma unroll
        for (int p = 0; p < 2; ++p) {
            int o = p * 4096 + tid * 16;
            gload16((const char*)(A  + (size_t)(bm + strow[p]) * 1024 + k0) + stcol[p],
                    (char*)&Als[buf][0][0] + o);
            gload16((const char*)(WT + (size_t)(bn + strow[p]) * 1024 + k0) + stcol[p],
                    (char*)&Bls[buf][0][0] + o);
        }
    };

    stage(0, 0);
    __syncthreads();

    for (int k0 = 0; k0 < 1024; k0 += 32) {
        const int buf = (k0 >> 5) & 1;
        if (k0 + 32 < 1024) stage(buf ^ 1, k0 + 32);   // overlap with compute

        bf8_t af[4], bfv[4];
        #pragma unroll
        for (int i = 0; i < 4; ++i) af[i]  = *(const bf8_t*)(&Als[buf][wr * 64 + i * 16 + lr][lg * 8]);
        #pragma unroll
        for (int j = 0; j < 4; ++j) bfv[j] = *(const bf8_t*)(&Bls[buf][wc * 64 + j * 16 + lr][lg * 8]);
        __builtin_amdgcn_s_setprio(1);
        #pragma unroll
        for (int i = 0; i < 4; ++i)
            #pragma unroll
            for (int j = 0; j < 4; ++j)
                acc[i][j] = MFMA16(af[i], bfv[j], acc[i][j]);
        __builtin_amdgcn_s_setprio(0);

        __syncthreads();
    }

    if (MODE == 0) {
        const float* bias = (blockIdx.z == 0) ? b0 : (blockIdx.z == 1) ? b1 : b2;
        const float sc = (blockIdx.z == 0) ? 0.18033688011112042f : 1.0f; // 0.125*log2(e)
        if (blockIdx.z < 2) {
            unsigned short* O = (unsigned short*)outp + (size_t)blockIdx.z * (8192 * 1024);
            #pragma unroll
            for (int i = 0; i < 4; ++i)
                #pragma unroll
                for (int j = 0; j < 4; ++j)
                    #pragma unroll
                    for (int r = 0; r < 4; ++r) {
                        int row = bm + wr * 64 + i * 16 + lg * 4 + r;
                        int col = bn + wc * 64 + j * 16 + lr;
                        float v = (acc[i][j][r] + bias[col]) * sc;
                        int b = row >> 11, s = row & 2047, h = col >> 6, d = col & 63;
                        O[(((size_t)(b * 16 + h)) * 2048 + s) * 64 + d] = f2bf(v);
                    }
        } else {
            // V^T: [bh][dh][s], key-permuted within 64-blocks (see header comment)
            unsigned short* OT = (unsigned short*)outp2;
            #pragma unroll
            for (int i = 0; i < 4; ++i)
                #pragma unroll
                for (int j = 0; j < 4; ++j)
                    #pragma unroll
                    for (int r = 0; r < 4; ++r) {
                        int row = bm + wr * 64 + i * 16 + lg * 4 + r;
                        int col = bn + wc * 64 + j * 16 + lr;
                        float v = acc[i][j][r] + bias[col];
                        int b = row >> 11, s = row & 2047, h = col >> 6, d = col & 63;
                        int kk = s & 63;
                        int sp = (s & ~63) | (((kk >> 4) & 2) << 4)    // mf_hi*32
                                           | (((kk >> 2) & 3) << 3)    // lg*8
                                           | (((kk >> 4) & 1) << 2)    // mf_lo*4
                                           | (kk & 3);                 // r
                        OT[(((size_t)(b * 16 + h)) * 64 + d) * 2048 + sp] = f2bf(v);
                    }
        }
    } else {
        float* O = (float*)outp;
        #pragma unroll
        for (int i = 0; i < 4; ++i)
            #pragma unroll
            for (int j = 0; j < 4; ++j)
                #pragma unroll
                for (int r = 0; r < 4; ++r) {
                    int row = bm + wr * 64 + i * 16 + lg * 4 + r;
                    int col = bn + wc * 64 + j * 16 + lr;
                    O[(size_t)row * 1024 + col] = acc[i][j][r] + b0[col];
                }
    }
}

// ---------- flash attention: all-register softmax/P, x32 PV via permuted V^T ----------
// grid 1024: 16 q-tiles x 64 heads, XCD-grouped. 4 waves x 32 q-rows (2 subtiles).
__global__ __launch_bounds__(256) void k_attn(
    const unsigned short* __restrict__ Q,    // [64][2048][64], pre-scaled by 0.125*log2e
    const unsigned short* __restrict__ K,    // [64][2048][64]
    const unsigned short* __restrict__ VT,   // [64][64][2048], key-permuted per 64-block
    const float* __restrict__ fbias,         // [4][2048] 0/-1e30
    unsigned short* __restrict__ O)          // [8192][1024]
{
    __shared__ __align__(16) unsigned short Kls[2][64][64];  // [buf][key][d], XOR-swizzled
    __shared__ __align__(16) unsigned short Vls[2][64][64];  // [buf][d][pos], XOR-swizzled
    const int tid  = threadIdx.x;
    const int lane = tid & 63;
    const int w    = tid >> 6;
    const int lg   = lane >> 4, lr = lane & 15;
    const int lg4  = lg * 4;

    const int id = blockIdx.x;
    const int bh = (id & 7) * 8 + ((id >> 3) & 7);   // XCD (id&7) owns 8 heads
    const int qt = id >> 6;                           // 0..15
    const int b  = bh >> 4, h = bh & 15;
    const int q0 = qt * 128 + w * 32;
    const size_t base = (size_t)bh * (2048 * 64);

    const char* Kbase = (const char*)(K + base);
    const char* Vbase = (const char*)(VT + (size_t)bh * (64 * 2048));

    int srow[2], scol[2];
    #pragma unroll
    for (int p = 0; p < 2; ++p) {
        int o = p * 4096 + tid * 16;
        srow[p] = o >> 7;
        scol[p] = (o & 127) ^ ((srow[p] & 7) << 4);   // inverse swizzle on global src
    }

    auto stage = [&](int buf, int k0) {
        #pragma unroll
        for (int p = 0; p < 2; ++p) {
            int o = p * 4096 + tid * 16;
            gload16(Kbase + (size_t)(k0 + srow[p]) * 128 + scol[p],
                    (char*)&Kls[buf][0][0] + o);
            gload16(Vbase + (size_t)srow[p] * 4096 + (size_t)k0 * 2 + scol[p],
                    (char*)&Vls[buf][0][0] + o);
        }
    };

    // Q fragments, 2 subtiles (B-operand: lane holds Q[q=lr][dh=lg*8..])
    bf8_t qf[2][2];
    #pragma unroll
    for (int sub = 0; sub < 2; ++sub) {
        const unsigned short* qp = Q + base + (size_t)(q0 + sub * 16 + lr) * 64 + lg * 8;
        qf[sub][0] = *(const bf8_t*)qp;
        qf[sub][1] = *(const bf8_t*)(qp + 32);
    }

    const f4_t z4 = {0.f, 0.f, 0.f, 0.f};
    f4_t oacc[2][4];                 // [sub][nf]: O^T[d=nf*16+lg4+r][q=lr]
    #pragma unroll
    for (int sub = 0; sub < 2; ++sub)
        #pragma unroll
        for (int nf = 0; nf < 4; ++nf) oacc[sub][nf] = z4;
    float mrow[2] = {-1e28f, -1e28f};
    float lsum[2] = {0.f, 0.f};

    const float* fb = fbias + b * 2048 + lg4;
    const int sw = (lr & 7) << 4;
    const int cA = (lg * 16) ^ sw;          // K frag cols
    const int cB = (64 + lg * 16) ^ sw;
    const int vA = (16 * lg) ^ sw;          // V frag cols (chunk 0 / 1)
    const int vB = (64 + 16 * lg) ^ sw;

    // softmax on 16 in-register scores -> packed bf16 P (u2 per 16-key chunk)
    auto sm = [&](f4_t (&s)[4], float& mr, float& ls, f4_t (&oa)[4], u2_t (&pf)[4]) {
        float a0 = fmaxf(fmaxf(fmaxf(s[0][0], s[0][1]), s[0][2]), s[0][3]);
        float a1 = fmaxf(fmaxf(fmaxf(s[1][0], s[1][1]), s[1][2]), s[1][3]);
        float a2 = fmaxf(fmaxf(fmaxf(s[2][0], s[2][1]), s[2][2]), s[2][3]);
        float a3 = fmaxf(fmaxf(fmaxf(s[3][0], s[3][1]), s[3][2]), s[3][3]);
        float smax = fmaxf(fmaxf(a0, a1), fmaxf(a2, a3));
        smax = fmaxf(smax, __shfl_xor(smax, 16));
        smax = fmaxf(smax, __shfl_xor(smax, 32));
        if (__any(smax > mr + 6.0f)) {          // defer-max (T13, THR=6 -> P <= 64)
            float mnew = fmaxf(mr, smax);
            float c = EXP2(mr - mnew);
            mr = mnew;
            ls *= c;
            #pragma unroll
            for (int nf = 0; nf < 4; ++nf) oa[nf] *= c;   // lane owns q=lr: scalar mul
        }
        #pragma unroll
        for (int mf = 0; mf < 4; ++mf) {
            float p0 = EXP2(s[mf][0] - mr);
            float p1 = EXP2(s[mf][1] - mr);
            float p2 = EXP2(s[mf][2] - mr);
            float p3 = EXP2(s[mf][3] - mr);
            ls += (p0 + p1) + (p2 + p3);
            u2_t u;
            u.x = cvtpk_bf16(p0, p1);
            u.y = cvtpk_bf16(p2, p3);
            pf[mf] = u;
        }
    };

    stage(0, 0);
    __syncthreads();

    for (int t = 0; t < 32; ++t) {
        const int cur = t & 1;
        if (t < 31) stage(cur ^ 1, (t + 1) * 64);    // async prefetch into other buffer
        const int k0 = t * 64;

        // mask bias -> QK accumulator C-init (C[key][q] = fbias[key], q-independent)
        f4_t cb[4];
        #pragma unroll
        for (int mf = 0; mf < 4; ++mf)
            cb[mf] = *(const f4_t*)(fb + k0 + mf * 16);

        // K fragments (swizzled LDS reads)
        bf8_t kf[4][2];
        #pragma unroll
        for (int mf = 0; mf < 4; ++mf) {
            const char* kr = (const char*)&Kls[cur][mf * 16 + lr][0];
            kf[mf][0] = *(const bf8_t*)(kr + cA);
            kf[mf][1] = *(const bf8_t*)(kr + cB);
        }

        // S^T = K·Q^T + bias: lane holds S[key=16mf+lg4+r][q=lr]
        f4_t s0[4], s1[4];
        __builtin_amdgcn_s_setprio(1);
        #pragma unroll
        for (int mf = 0; mf < 4; ++mf) {
            s0[mf] = MFMA16(kf[mf][1], qf[0][1], MFMA16(kf[mf][0], qf[0][0], cb[mf]));
            s1[mf] = MFMA16(kf[mf][1], qf[1][1], MFMA16(kf[mf][0], qf[1][0], cb[mf]));
        }
        __builtin_amdgcn_s_setprio(0);

        // V^T A-fragments (contiguous b128 thanks to key permutation);
        // issued here so ds latency hides under the softmax VALU chain
        bf8_t vf[4][2];   // [nf][chunk]: A[row=d=nf*16+lr][k=lg*8+e] for keys chunk*32..+31
        #pragma unroll
        for (int nf = 0; nf < 4; ++nf) {
            const char* vr = (const char*)&Vls[cur][nf * 16 + lr][0];
            vf[nf][0] = *(const bf8_t*)(vr + vA);
            vf[nf][1] = *(const bf8_t*)(vr + vB);
        }

        u2_t pf0[4], pf1[4];
        sm(s0, mrow[0], lsum[0], oacc[0], pf0);
        sm(s1, mrow[1], lsum[1], oacc[1], pf1);

        // PV: D[d][q] += V^T · P, two 32-key x32 MFMAs per nf per sub.
        // B-operand = concat(pf[2c], pf[2c+1]) — register-level, no data movement.
        __builtin_amdgcn_s_setprio(1);
        #pragma unroll
        for (int c = 0; c < 2; ++c) {
            u4_t up0, up1;
            up0.x = pf0[2*c].x; up0.y = pf0[2*c].y; up0.z = pf0[2*c+1].x; up0.w = pf0[2*c+1].y;
            up1.x = pf1[2*c].x; up1.y = pf1[2*c].y; up1.z = pf1[2*c+1].x; up1.w = pf1[2*c+1].y;
            bf8_t pb0 = __builtin_bit_cast(bf8_t, up0);
            bf8_t pb1 = __builtin_bit_cast(bf8_t, up1);
            #pragma unroll
            for (int nf = 0; nf < 4; ++nf) {
                oacc[0][nf] = MFMA16(vf[nf][c], pb0, oacc[0][nf]);
                oacc[1][nf] = MFMA16(vf[nf][c], pb1, oacc[1][nf]);
            }
        }
        __builtin_amdgcn_s_setprio(0);

        __syncthreads();   // drains vmcnt(0): prefetch landed; all waves done with cur
    }

    // normalize + write [B,S,D] bf16 (lane owns q=lr, d=nf*16+lg4+0..3)
    #pragma unroll
    for (int sub = 0; sub < 2; ++sub) {
        float lt = lsum[sub];
        lt += __shfl_xor(lt, 16);
        lt += __shfl_xor(lt, 32);
        float inv = 1.0f / lt;
        int qrow = q0 + sub * 16 + lr;
        size_t ob = ((size_t)(b * 2048 + qrow)) * 1024 + h * 64 + lg4;
        #pragma unroll
        for (int nf = 0; nf < 4; ++nf) {
            u2_t uo;
            uo.x = cvtpk_bf16(oacc[sub][nf][0] * inv, oacc[sub][nf][1] * inv);
            uo.y = cvtpk_bf16(oacc[sub][nf][2] * inv, oacc[sub][nf][3] * inv);
            *(u2_t*)(O + ob + nf * 16) = uo;
        }
    }
}

// ---------- launch ----------
extern "C" void kernel_launch(void* const* d_in, const int* in_sizes, int n_in,
                              void* d_out, int out_size, void* d_ws, size_t ws_size,
                              hipStream_t stream) {
    const float* x  = (const float*)d_in[0];
    const void*  mask = d_in[1];
    const float* Wq = (const float*)d_in[2];
    const float* bq = (const float*)d_in[3];
    const float* Wk = (const float*)d_in[4];
    const float* bk = (const float*)d_in[5];
    const float* Wv = (const float*)d_in[6];
    const float* bv = (const float*)d_in[7];
    const float* Wo = (const float*)d_in[8];
    const float* bo = (const float*)d_in[9];

    char* ws = (char*)d_ws;
    float*          fbias = (float*)(ws + 1024);
    unsigned short* xb    = (unsigned short*)(ws + 65536);                // 16 MiB
    unsigned short* wT    = (unsigned short*)(ws + 65536 + 16777216);     // 8 MiB
    unsigned short* qkv   = (unsigned short*)(ws + 65536 + 25165824);     // 48 MiB (Q,K,VT)
    unsigned short* attnb = (unsigned short*)(ws + 65536 + 75497472);     // 16 MiB

    unsigned short* Qb = qkv;
    unsigned short* Kb = qkv + 8388608;
    unsigned short* VT = qkv + 16777216;   // written (key-permuted) by GEMM z==2 epilogue

    k_bias<<<1, 1024, 0, stream>>>(mask, fbias);
    k_cvt<<<8192, 256, 0, stream>>>(x, xb, 2097152);
    k_transw<<<dim3(32, 32, 4), dim3(32, 8), 0, stream>>>(Wq, Wk, Wv, Wo, wT);
    k_gemm<0><<<dim3(8, 64, 3), 256, 0, stream>>>(xb, wT, bq, bk, bv, (void*)qkv, (void*)VT);
    k_attn<<<1024, 256, 0, stream>>>(Qb, Kb, VT, fbias, attnb);
    k_gemm<1><<<dim3(8, 64, 1), 256, 0, stream>>>(attnb, wT + 3145728, bo, bo, bo, d_out, nullptr);
}